// Round 8
// baseline (361.384 us; speedup 1.0000x reference)
//
#include <hip/hip_runtime.h>
#include <math.h>

#define N_USERS 100000
#define N_ITEMS 50000
#define NR      150000
#define N_EDGES 2000000
#define D       64
#define EPS     1e-12f

#define UPAD 64      // user bucket capacity  (deg ~ Poisson(20); P(>64) ~ 1e-13)
#define IPAD 64      // item bucket capacity  (deg ~ Poisson(40); ~few rows spill -> ovf)
#define OVF_CAP 4096

#define NPART 8      // XCDs (blockIdx % 8 lands on XCD p under round-robin dispatch)
#define NSUB  2      // sequential row sub-chunks per XCD (shrinks L2-resident set)
#define NCHUNK (NPART * NSUB)          // 16 row chunks
#define UCH (N_USERS / NCHUNK)         // 6250 user rows per chunk
#define ICH (N_ITEMS / NCHUNK)         // 3125 item rows per chunk
#define FILL_BPP 256                   // fill blocks per partition
#define FILL_BLOCKS (NPART * FILL_BPP) // 2048

// ---------------- Tier-A4 workspace layout (bytes) ----------------
// scal : float4[NR]              @ 0             2,400,000
// xh   : ushort[NR*64]           @ 2,400,000    19,200,000
// cnt  : int[NR]                 @ 21,600,000      600,000
// ubkt : u16[N_USERS*UPAD]       @ 22,200,000   12,800,000
// ibkt : u32[N_ITEMS*IPAD]       @ 35,000,000   12,800,000
// ovfc : int                     @ 47,800,000            4
// ovf  : int[OVF_CAP]            @ 47,800,004       16,384
#define SCAL_OFF 0u
#define XH_OFF   2400000u
#define CNT_OFF  21600000u
#define UBKT_OFF 22200000u
#define IBKT_OFF 35000000u
#define OVFC_OFF 47800000u
#define OVF_OFF  47800004u
#define WS_A4    47816388u

// ---------------- Tier-C (round-3 proven) layout ----------------
#define C_SCAL 0u
#define C_HEAD 2400000u
#define C_NXTU 3000000u
#define C_NXTI 11000000u
#define WS_C   19000000u

__device__ __forceinline__ unsigned short f2bf(float v) {
    unsigned int b = __float_as_uint(v);
    b += 0x7FFFu + ((b >> 16) & 1u);          // round-to-nearest-even
    return (unsigned short)(b >> 16);
}
#define BF_LO(w) __uint_as_float((w) << 16)
#define BF_HI(w) __uint_as_float((w) & 0xFFFF0000u)

// ---------------------------------------------------------------------------
// Per-row scalars + bf16 copy of x.  scal[r] = {invn, rsqrt(deg), beta, 0}
// Runs ALONE (before fill) so its 57 MB stream does not evict fill's hot set.
// ---------------------------------------------------------------------------
__global__ void prep_kernel(const float* __restrict__ x,
                            const float* __restrict__ beta,
                            const float* __restrict__ du,
                            const float* __restrict__ di,
                            float4* __restrict__ scal,
                            unsigned short* __restrict__ xh) {
    int gid  = blockIdx.x * blockDim.x + threadIdx.x;
    int r    = gid >> 6;
    int lane = gid & 63;
    if (r >= NR) return;

    float v = x[r * D + lane];
    xh[r * D + lane] = f2bf(v);

    float ss = v * v;
    #pragma unroll
    for (int m = 32; m >= 1; m >>= 1) ss += __shfl_xor(ss, m);

    if (lane == 0) {
        float invn = 1.0f / fmaxf(sqrtf(ss), EPS);
        float deg  = (r < N_USERS) ? du[r] : di[r - N_USERS];
        float b    = (r < N_USERS) ? beta[r] : 0.0f;
        scal[r] = make_float4(invn, rsqrtf(deg), b, 0.0f);
    }
}

// ---------------------------------------------------------------------------
// DEDICATED XCD-partitioned bucket fill (no co-resident pollution).
// XCD p (= blockIdx%8) sequentially handles row chunks {2p, 2p+1}; per
// sub-pass hot set (cnt+bucket slices) ~1.85 MB << 4 MB private L2, and the
// only other traffic is the nontemporal edge stream -> bucket lines should
// survive between touches and evict ~once.
// ---------------------------------------------------------------------------
__global__ void fillx_kernel(const int* __restrict__ u,
                             const int* __restrict__ i,
                             int* __restrict__ cnt,
                             unsigned short* __restrict__ ubkt,
                             unsigned int* __restrict__ ibkt,
                             int* __restrict__ ovfc,
                             int* __restrict__ ovf) {
    int p   = blockIdx.x & (NPART - 1);
    int qb  = blockIdx.x >> 3;
    int tid = qb * blockDim.x + threadIdx.x;
    const int stride = FILL_BPP * 256;

    #pragma unroll
    for (int sub = 0; sub < NSUB; ++sub) {
        int c   = p * NSUB + sub;
        int ulo = c * UCH, uhi = ulo + UCH;
        int ilo = c * ICH, ihi = ilo + ICH;

        for (int e = tid; e < N_EDGES; e += stride) {
            int uu = __builtin_nontemporal_load(u + e);
            int ii = __builtin_nontemporal_load(i + e);

            if (uu >= ulo && uu < uhi) {
                int s = atomicAdd(&cnt[uu], 1);
                if (s < UPAD) {
                    ubkt[(size_t)uu * UPAD + s] = (unsigned short)ii;
                } else {
                    int pp = atomicAdd(ovfc, 1);
                    if (pp < OVF_CAP) ovf[pp] = (e << 1);
                }
            }
            if (ii >= ilo && ii < ihi) {
                int s = atomicAdd(&cnt[N_USERS + ii], 1);
                if (s < IPAD) {
                    ibkt[(size_t)ii * IPAD + s] = (unsigned int)uu;
                } else {
                    int pp = atomicAdd(ovfc, 1);
                    if (pp < OVF_CAP) ovf[pp] = (e << 1) | 1;
                }
            }
        }
    }
}

// ---------------------------------------------------------------------------
// Unified gather over all NR rows: wave per row, 8 neighbors/iter, chase-free.
// lane = (g = lane>>3 slot, q = lane&7 dim octet).
// ---------------------------------------------------------------------------
__global__ void gatherA_kernel(const unsigned short* __restrict__ xh,
                               const float4* __restrict__ scal,
                               const int* __restrict__ cnt,
                               const unsigned short* __restrict__ ubkt,
                               const unsigned int* __restrict__ ibkt,
                               float* __restrict__ out) {
    int gid  = blockIdx.x * blockDim.x + threadIdx.x;
    int r    = gid >> 6;
    int lane = gid & 63;
    if (r >= NR) return;

    int g = lane >> 3;
    int q = lane & 7;

    float4 sc = scal[r];
    uint4 hs = *(const uint4*)(xh + (size_t)r * D + q * 8);
    float xs0 = BF_LO(hs.x), xs1 = BF_HI(hs.x);
    float xs2 = BF_LO(hs.y), xs3 = BF_HI(hs.y);
    float xs4 = BF_LO(hs.z), xs5 = BF_HI(hs.z);
    float xs6 = BF_LO(hs.w), xs7 = BF_HI(hs.w);

    float a0=0.f,a1=0.f,a2=0.f,a3=0.f,a4=0.f,a5=0.f,a6=0.f,a7=0.f;

    if (r < N_USERS) {
        int deg = cnt[r];
        if (deg > UPAD) deg = UPAD;
        int iters = (deg + 7) >> 3;

        for (int it = 0; it < iters; ++it) {
            int idx = it * 8 + g;
            bool valid = (idx < deg);
            int nb = N_USERS + (int)ubkt[(size_t)r * UPAD + (valid ? idx : 0)];

            float4 so = scal[nb];
            uint4 ho = *(const uint4*)(xh + (size_t)nb * D + q * 8);
            float o0 = BF_LO(ho.x), o1 = BF_HI(ho.x);
            float o2 = BF_LO(ho.y), o3 = BF_HI(ho.y);
            float o4 = BF_LO(ho.z), o5 = BF_HI(ho.z);
            float o6 = BF_LO(ho.w), o7 = BF_HI(ho.w);

            float p = xs0*o0 + xs1*o1 + xs2*o2 + xs3*o3
                    + xs4*o4 + xs5*o5 + xs6*o6 + xs7*o7;
            p += __shfl_xor(p, 1);
            p += __shfl_xor(p, 2);
            p += __shfl_xor(p, 4);

            float sv  = p * sc.x * so.x - sc.z;          // own beta
            float sig = 1.0f / (1.0f + __expf(-sv));
            float w   = 4.0f * sig * (1.0f - sig) * sc.y * so.y;
            w = valid ? w : 0.0f;

            a0 = fmaf(w, o0, a0); a1 = fmaf(w, o1, a1);
            a2 = fmaf(w, o2, a2); a3 = fmaf(w, o3, a3);
            a4 = fmaf(w, o4, a4); a5 = fmaf(w, o5, a5);
            a6 = fmaf(w, o6, a6); a7 = fmaf(w, o7, a7);
        }
    } else {
        int ri = r - N_USERS;
        int deg = cnt[r];
        if (deg > IPAD) deg = IPAD;
        int iters = (deg + 7) >> 3;

        for (int it = 0; it < iters; ++it) {
            int idx = it * 8 + g;
            bool valid = (idx < deg);
            int nb = (int)ibkt[(size_t)ri * IPAD + (valid ? idx : 0)];

            float4 so = scal[nb];
            uint4 ho = *(const uint4*)(xh + (size_t)nb * D + q * 8);
            float o0 = BF_LO(ho.x), o1 = BF_HI(ho.x);
            float o2 = BF_LO(ho.y), o3 = BF_HI(ho.y);
            float o4 = BF_LO(ho.z), o5 = BF_HI(ho.z);
            float o6 = BF_LO(ho.w), o7 = BF_HI(ho.w);

            float p = xs0*o0 + xs1*o1 + xs2*o2 + xs3*o3
                    + xs4*o4 + xs5*o5 + xs6*o6 + xs7*o7;
            p += __shfl_xor(p, 1);
            p += __shfl_xor(p, 2);
            p += __shfl_xor(p, 4);

            float sv  = p * sc.x * so.x - so.z;          // neighbor (user) beta
            float sig = 1.0f / (1.0f + __expf(-sv));
            float w   = 4.0f * sig * (1.0f - sig) * sc.y * so.y;
            w = valid ? w : 0.0f;

            a0 = fmaf(w, o0, a0); a1 = fmaf(w, o1, a1);
            a2 = fmaf(w, o2, a2); a3 = fmaf(w, o3, a3);
            a4 = fmaf(w, o4, a4); a5 = fmaf(w, o5, a5);
            a6 = fmaf(w, o6, a6); a7 = fmaf(w, o7, a7);
        }
    }

    #pragma unroll
    for (int m = 8; m <= 32; m <<= 1) {
        a0 += __shfl_xor(a0, m); a1 += __shfl_xor(a1, m);
        a2 += __shfl_xor(a2, m); a3 += __shfl_xor(a3, m);
        a4 += __shfl_xor(a4, m); a5 += __shfl_xor(a5, m);
        a6 += __shfl_xor(a6, m); a7 += __shfl_xor(a7, m);
    }

    if (g == 0) {
        float4* o4p = (float4*)(out + (size_t)r * D + q * 8);
        o4p[0] = make_float4(a0, a1, a2, a3);
        o4p[1] = make_float4(a4, a5, a6, a7);
    }
}

// ---------------------------------------------------------------------------
// Overflow fixer: recompute w for spilled edges (fp32), atomic-add into the
// overflowed side's row. Expect ~0-20 edges.
// ---------------------------------------------------------------------------
__global__ void ovf_kernel(const float* __restrict__ x,
                           const float4* __restrict__ scal,
                           const int* __restrict__ u,
                           const int* __restrict__ i,
                           const int* __restrict__ ovfc,
                           const int* __restrict__ ovf,
                           float* __restrict__ out) {
    int n = *ovfc;
    if (n > OVF_CAP) n = OVF_CAP;
    int gid  = blockIdx.x * blockDim.x + threadIdx.x;
    int wave = gid >> 6;
    int lane = gid & 63;
    int nw   = (gridDim.x * blockDim.x) >> 6;

    for (int k = wave; k < n; k += nw) {
        int pk = ovf[k];
        int e = pk >> 1, side = pk & 1;
        int uu = u[e];
        int ir = N_USERS + i[e];
        float xu = x[uu * D + lane];
        float xi = x[ir * D + lane];
        float p = xu * xi;
        #pragma unroll
        for (int m = 32; m >= 1; m >>= 1) p += __shfl_xor(p, m);
        float4 su = scal[uu];
        float4 si = scal[ir];
        float sv  = p * su.x * si.x - su.z;
        float sig = 1.0f / (1.0f + __expf(-sv));
        float w   = 4.0f * sig * (1.0f - sig) * su.y * si.y;
        if (side == 0) atomicAdd(&out[(size_t)uu * D + lane], w * xi);
        else           atomicAdd(&out[(size_t)ir * D + lane], w * xu);
    }
}

// ---------------------------------------------------------------------------
// Tier C (round-3 proven linked-list path)
// ---------------------------------------------------------------------------
__global__ void scal_kernel(const float* __restrict__ x,
                            const float* __restrict__ beta,
                            const float* __restrict__ du,
                            const float* __restrict__ di,
                            float4* __restrict__ scal) {
    int gid  = blockIdx.x * blockDim.x + threadIdx.x;
    int r    = gid >> 6;
    int lane = gid & 63;
    if (r >= NR) return;
    float v  = x[r * D + lane];
    float ss = v * v;
    #pragma unroll
    for (int m = 32; m >= 1; m >>= 1) ss += __shfl_xor(ss, m);
    if (lane == 0) {
        float invn = 1.0f / fmaxf(sqrtf(ss), EPS);
        float deg  = (r < N_USERS) ? du[r] : di[r - N_USERS];
        float b    = (r < N_USERS) ? beta[r] : 0.0f;
        scal[r] = make_float4(invn, rsqrtf(deg), b, 0.0f);
    }
}

__global__ void link_kernel(const int* __restrict__ u,
                            const int* __restrict__ i,
                            int* __restrict__ head,
                            int* __restrict__ next_u,
                            int* __restrict__ next_i) {
    int e = blockIdx.x * blockDim.x + threadIdx.x;
    if (e >= N_EDGES) return;
    int uu = u[e];
    int ii = N_USERS + i[e];
    next_u[e] = atomicExch(&head[uu], e);
    next_i[e] = atomicExch(&head[ii], e);
}

__global__ void gather_kernel(const float4* __restrict__ x4,
                              const float4* __restrict__ scal,
                              const int* __restrict__ head,
                              const int* __restrict__ next_u,
                              const int* __restrict__ next_i,
                              const int* __restrict__ u,
                              const int* __restrict__ i,
                              float4* __restrict__ out4) {
    int gid  = blockIdx.x * blockDim.x + threadIdx.x;
    int r    = gid >> 6;
    int lane = gid & 63;
    if (r >= NR) return;
    int g = lane >> 4;
    int q = lane & 15;
    bool isu = (r < N_USERS);
    const int* __restrict__ nxt = isu ? next_u : next_i;
    const int* __restrict__ oid = isu ? i : u;
    int obase = isu ? N_USERS : 0;
    float4 sc = scal[r];
    float4 xs = x4[r * 16 + q];
    float4 acc = make_float4(0.f, 0.f, 0.f, 0.f);
    int e  = head[r];
    int c0 = e; { int t = nxt[(c0 >= 0) ? c0 : 0]; e = (c0 >= 0) ? t : -1; }
    int c1 = e; { int t = nxt[(c1 >= 0) ? c1 : 0]; e = (c1 >= 0) ? t : -1; }
    int c2 = e; { int t = nxt[(c2 >= 0) ? c2 : 0]; e = (c2 >= 0) ? t : -1; }
    int c3 = e; { int t = nxt[(c3 >= 0) ? c3 : 0]; e = (c3 >= 0) ? t : -1; }
    while (c0 >= 0) {
        int n0 = e; { int t = nxt[(n0 >= 0) ? n0 : 0]; e = (n0 >= 0) ? t : -1; }
        int n1 = e; { int t = nxt[(n1 >= 0) ? n1 : 0]; e = (n1 >= 0) ? t : -1; }
        int n2 = e; { int t = nxt[(n2 >= 0) ? n2 : 0]; e = (n2 >= 0) ? t : -1; }
        int n3 = e; { int t = nxt[(n3 >= 0) ? n3 : 0]; e = (n3 >= 0) ? t : -1; }
        int eg = (g == 0) ? c0 : (g == 1) ? c1 : (g == 2) ? c2 : c3;
        bool valid = (eg >= 0);
        int  es = valid ? eg : c0;
        int  nb = obase + oid[es];
        float4 so = scal[nb];
        float4 xo = x4[nb * 16 + q];
        float p = xs.x * xo.x + xs.y * xo.y + xs.z * xo.z + xs.w * xo.w;
        p += __shfl_xor(p, 1);
        p += __shfl_xor(p, 2);
        p += __shfl_xor(p, 4);
        p += __shfl_xor(p, 8);
        float b   = isu ? sc.z : so.z;
        float sv  = p * sc.x * so.x - b;
        float sig = 1.0f / (1.0f + __expf(-sv));
        float w   = 4.0f * sig * (1.0f - sig) * sc.y * so.y;
        w = valid ? w : 0.0f;
        acc.x = fmaf(w, xo.x, acc.x);
        acc.y = fmaf(w, xo.y, acc.y);
        acc.z = fmaf(w, xo.z, acc.z);
        acc.w = fmaf(w, xo.w, acc.w);
        c0 = n0; c1 = n1; c2 = n2; c3 = n3;
    }
    acc.x += __shfl_xor(acc.x, 16); acc.y += __shfl_xor(acc.y, 16);
    acc.z += __shfl_xor(acc.z, 16); acc.w += __shfl_xor(acc.w, 16);
    acc.x += __shfl_xor(acc.x, 32); acc.y += __shfl_xor(acc.y, 32);
    acc.z += __shfl_xor(acc.z, 32); acc.w += __shfl_xor(acc.w, 32);
    if (g == 0) out4[r * 16 + q] = acc;
}

// ---------------------------------------------------------------------------
// Tier D (round-1 atomic fallback)
// ---------------------------------------------------------------------------
__global__ void norm_kernel(const float* __restrict__ x,
                            float* __restrict__ invn,
                            int nrows) {
    int gid  = blockIdx.x * blockDim.x + threadIdx.x;
    int wave = gid >> 6;
    int lane = gid & 63;
    if (wave >= nrows) return;
    float v  = x[wave * D + lane];
    float ss = v * v;
    #pragma unroll
    for (int m = 32; m >= 1; m >>= 1) ss += __shfl_xor(ss, m);
    if (lane == 0) invn[wave] = 1.0f / fmaxf(sqrtf(ss), EPS);
}

__global__ void edge_kernel(const float* __restrict__ x,
                            const float* __restrict__ beta,
                            const float* __restrict__ du,
                            const float* __restrict__ di,
                            const int*   __restrict__ u,
                            const int*   __restrict__ i,
                            const float* __restrict__ invn,
                            float* __restrict__ out) {
    int gid  = blockIdx.x * blockDim.x + threadIdx.x;
    int wave = gid >> 6;
    int lane = gid & 63;
    if (wave >= N_EDGES) return;
    int uu = u[wave];
    int ii = i[wave];
    const float xu = x[uu * D + lane];
    const float xi = x[(N_USERS + ii) * D + lane];
    float p = xu * xi;
    #pragma unroll
    for (int m = 32; m >= 1; m >>= 1) p += __shfl_xor(p, m);
    float s   = p * invn[uu] * invn[N_USERS + ii] - beta[uu];
    float sig = 1.0f / (1.0f + __expf(-s));
    float w   = 4.0f * sig * (1.0f - sig) * rsqrtf(du[uu]) * rsqrtf(di[ii]);
    atomicAdd(&out[uu * D + lane],             w * xi);
    atomicAdd(&out[(N_USERS + ii) * D + lane], w * xu);
}

// ---------------------------------------------------------------------------
extern "C" void kernel_launch(void* const* d_in, const int* in_sizes, int n_in,
                              void* d_out, int out_size, void* d_ws, size_t ws_size,
                              hipStream_t stream) {
    const float* x    = (const float*)d_in[0];
    const float* beta = (const float*)d_in[1];
    const float* du   = (const float*)d_in[2];
    const float* di   = (const float*)d_in[3];
    const int*   u    = (const int*)d_in[4];
    const int*   i    = (const int*)d_in[5];
    float* out = (float*)d_out;
    char*  ws  = (char*)d_ws;

    if (ws_size >= (size_t)WS_A4) {
        float4*         scal = (float4*)(ws + SCAL_OFF);
        unsigned short* xh   = (unsigned short*)(ws + XH_OFF);
        int*            cnt  = (int*)(ws + CNT_OFF);
        unsigned short* ubkt = (unsigned short*)(ws + UBKT_OFF);
        unsigned int*   ibkt = (unsigned int*)(ws + IBKT_OFF);
        int*            ovfc = (int*)(ws + OVFC_OFF);
        int*            ovf  = (int*)(ws + OVF_OFF);

        hipMemsetAsync(cnt, 0, (size_t)NR * sizeof(int), stream);
        hipMemsetAsync(ovfc, 0, sizeof(int), stream);
        prep_kernel<<<(NR + 3) / 4, 256, 0, stream>>>(x, beta, du, di, scal, xh);
        fillx_kernel<<<FILL_BLOCKS, 256, 0, stream>>>(u, i, cnt, ubkt, ibkt, ovfc, ovf);
        gatherA_kernel<<<(NR + 3) / 4, 256, 0, stream>>>(xh, scal, cnt, ubkt, ibkt, out);
        ovf_kernel<<<64, 256, 0, stream>>>(x, scal, u, i, ovfc, ovf, out);
    } else if (ws_size >= (size_t)WS_C) {
        float4* scal   = (float4*)(ws + C_SCAL);
        int*    head   = (int*)(ws + C_HEAD);
        int*    next_u = (int*)(ws + C_NXTU);
        int*    next_i = (int*)(ws + C_NXTI);

        scal_kernel<<<(NR + 3) / 4, 256, 0, stream>>>(x, beta, du, di, scal);
        hipMemsetAsync(head, 0xFF, (size_t)NR * sizeof(int), stream);
        link_kernel<<<(N_EDGES + 255) / 256, 256, 0, stream>>>(u, i, head, next_u, next_i);
        gather_kernel<<<(NR + 3) / 4, 256, 0, stream>>>((const float4*)x, scal, head,
                                                        next_u, next_i, u, i, (float4*)out);
    } else {
        float* invn = (float*)ws;
        hipMemsetAsync(d_out, 0, (size_t)out_size * sizeof(float), stream);
        norm_kernel<<<(NR + 3) / 4, 256, 0, stream>>>(x, invn, NR);
        edge_kernel<<<(N_EDGES + 3) / 4, 256, 0, stream>>>(x, beta, du, di, u, i, invn, out);
    }
}

// Round 9
// 348.253 us; speedup vs baseline: 1.0377x; 1.0377x over previous
//
#include <hip/hip_runtime.h>
#include <math.h>

#define N_USERS 100000
#define N_ITEMS 50000
#define NR      150000
#define N_EDGES 2000000
#define D       64
#define EPS     1e-12f

#define UPAD 48        // user bucket capacity (deg ~ Poisson(20); P(>48) ~ 3e-7)
#define IPAD 64        // item bucket capacity (deg ~ Poisson(40); few rows spill)
#define OVF_CAP 4096

#define NCHUNK 8       // row chunks == XCDs
#define UCH 12500      // users per chunk
#define ICH 6250       // items per chunk
#define SEGCAP 262144  // records per partition segment (mean 250K, sigma ~470)

#define EPT 8          // edges per thread in partition pass
#define PART_BLOCKS ((N_EDGES + 256*EPT - 1) / (256*EPT))   // 977
#define FILLP_BLOCKS 1024                                    // 128 per chunk

// ---------------- Tier-P workspace layout (bytes) ----------------
// scal : float4[NR]            @ 0             2,400,000
// xh   : ushort[NR*64]         @ 2,400,000    19,200,000
// cnt  : int[NR]               @ 21,600,000      600,000
// ubkt : u16[N_USERS*UPAD]     @ 22,200,000    9,600,000
// ibkt : u32[N_ITEMS*IPAD]     @ 31,800,000   12,800,000
// part : u32[8*SEGCAP]         @ 44,600,000    8,388,608
// ucur : int[8]                @ 52,988,608           32
// icur : int[8]                @ 52,988,640           32
// ovfc : int (+pad)            @ 52,988,672            8
// ovf  : int2[OVF_CAP]         @ 52,988,680       32,768
#define SCAL_OFF 0u
#define XH_OFF   2400000u
#define CNT_OFF  21600000u
#define UBKT_OFF 22200000u
#define IBKT_OFF 31800000u
#define PART_OFF 44600000u
#define UCUR_OFF 52988608u
#define ICUR_OFF 52988640u
#define OVFC_OFF 52988672u
#define OVF_OFF  52988680u
#define WS_P     53021448u

// ---------------- Tier-A fallback (round-6 proven, 47.8 MB) ----------------
#define A_SCAL 0u
#define A_XH   2400000u
#define A_CNT  21600000u
#define A_UBKT 22200000u        // u16[N_USERS*64] 12.8 MB
#define A_IBKT 35000000u        // u32[N_ITEMS*64] 12.8 MB
#define A_OVFC 47800000u
#define A_OVF  47800008u        // int2[OVF_CAP]
#define WS_A   47832776u
#define A_UPAD 64
#define A_IPAD 64

__device__ __forceinline__ unsigned short f2bf(float v) {
    unsigned int b = __float_as_uint(v);
    b += 0x7FFFu + ((b >> 16) & 1u);          // round-to-nearest-even
    return (unsigned short)(b >> 16);
}
#define BF_LO(w) __uint_as_float((w) << 16)
#define BF_HI(w) __uint_as_float((w) & 0xFFFF0000u)

// ---------------------------------------------------------------------------
// cursors + ovf counter init
// ---------------------------------------------------------------------------
__global__ void init_kernel(int* ucur, int* icur, int* ovfc) {
    int t = threadIdx.x;
    if (t < NCHUNK) { ucur[t] = t * SEGCAP; icur[t] = t * SEGCAP; }
    if (t == 32) *ovfc = 0;
}

// ---------------------------------------------------------------------------
// Per-row scalars + bf16 copy of x.  scal[r] = {invn, rsqrt(deg), beta, 0}
// ---------------------------------------------------------------------------
__global__ void prep_kernel(const float* __restrict__ x,
                            const float* __restrict__ beta,
                            const float* __restrict__ du,
                            const float* __restrict__ di,
                            float4* __restrict__ scal,
                            unsigned short* __restrict__ xh) {
    int gid  = blockIdx.x * blockDim.x + threadIdx.x;
    int r    = gid >> 6;
    int lane = gid & 63;
    if (r >= NR) return;

    float v = x[r * D + lane];
    xh[r * D + lane] = f2bf(v);

    float ss = v * v;
    #pragma unroll
    for (int m = 32; m >= 1; m >>= 1) ss += __shfl_xor(ss, m);

    if (lane == 0) {
        float invn = 1.0f / fmaxf(sqrtf(ss), EPS);
        float deg  = (r < N_USERS) ? du[r] : di[r - N_USERS];
        float b    = (r < N_USERS) ? beta[r] : 0.0f;
        scal[r] = make_float4(invn, rsqrtf(deg), b, 0.0f);
    }
}

// ---------------------------------------------------------------------------
// P1: LDS-histogram partition of edges into 8 row-chunk segments.
// SIDE 0: bin by user chunk, record = (u_local<<16)|i   (14+16 bits)
// SIDE 1: bin by item chunk, record = (i_local<<17)|u   (13+17 bits)
// One global atomic per (block, bin). Writes are per-bin contiguous bursts.
// ---------------------------------------------------------------------------
template<int SIDE>
__global__ void part_kernel(const int* __restrict__ u,
                            const int* __restrict__ i,
                            int* __restrict__ cur,
                            unsigned int* __restrict__ part,
                            int* __restrict__ ovfc,
                            int2* __restrict__ ovf) {
    __shared__ int h[NCHUNK];
    __shared__ int base[NCHUNK];

    int tid = threadIdx.x;
    int e0  = blockIdx.x * (256 * EPT);
    if (tid < NCHUNK) h[tid] = 0;
    __syncthreads();

    int bins[EPT];
    unsigned int vals[EPT];
    int uus[EPT], iis[EPT];

    #pragma unroll
    for (int k = 0; k < EPT; ++k) {
        int e = e0 + k * 256 + tid;                 // coalesced
        bool ok = (e < N_EDGES);
        int uu = ok ? __builtin_nontemporal_load(u + e) : 0;
        int ii = ok ? __builtin_nontemporal_load(i + e) : 0;
        int bin, loc;
        unsigned int val;
        if (SIDE == 0) { bin = uu / UCH; loc = uu - bin * UCH;
                         val = ((unsigned)loc << 16) | (unsigned)ii; }
        else           { bin = ii / ICH; loc = ii - bin * ICH;
                         val = ((unsigned)loc << 17) | (unsigned)uu; }
        bins[k] = ok ? bin : -1;
        vals[k] = val; uus[k] = uu; iis[k] = ii;
        if (ok) atomicAdd(&h[bin], 1);
    }
    __syncthreads();
    if (tid < NCHUNK) { base[tid] = atomicAdd(&cur[tid], h[tid]); h[tid] = 0; }
    __syncthreads();

    #pragma unroll
    for (int k = 0; k < EPT; ++k) {
        int b = bins[k];
        if (b >= 0) {
            int r   = atomicAdd(&h[b], 1);
            int off = base[b] + r;
            if (off < (b + 1) * SEGCAP) {
                part[off] = vals[k];
            } else {                                   // segment overflow (≈never)
                int pp = atomicAdd(ovfc, 1);
                if (pp < OVF_CAP) {
                    int2 rec = (SIDE == 0)
                      ? make_int2(uus[k], N_USERS + iis[k])
                      : make_int2(N_USERS + iis[k], uus[k]);
                    ovf[pp] = rec;
                }
            }
        }
    }
}

// ---------------------------------------------------------------------------
// P2: bucket fill from partitioned records. Chunk c pinned to XCD c
// (blockIdx%8). Per-chunk stream ~1 MB + bucket slice ~1.2-1.6 MB -> fits
// the XCD's private 4 MB L2; dirty bucket lines evict ~once.
// ---------------------------------------------------------------------------
template<int SIDE>
__global__ void fillp_kernel(const unsigned int* __restrict__ part,
                             const int* __restrict__ cur,      // final cursors
                             int* __restrict__ cnt,
                             unsigned short* __restrict__ ubkt,
                             unsigned int* __restrict__ ibkt,
                             int* __restrict__ ovfc,
                             int2* __restrict__ ovf) {
    int p  = blockIdx.x & (NCHUNK - 1);
    int jb = blockIdx.x >> 3;                        // 0..127
    int lo = p * SEGCAP;
    int hi = cur[p];                                 // lo + count (cap'ed writes)
    if (hi > (p + 1) * SEGCAP) hi = (p + 1) * SEGCAP;

    for (int k = lo + jb * 256 + (int)threadIdx.x; k < hi; k += 128 * 256) {
        unsigned int rec = __builtin_nontemporal_load(part + k);
        if (SIDE == 0) {
            int loc = rec >> 16;
            int ii  = rec & 0xFFFF;
            int uu  = p * UCH + loc;
            int s = atomicAdd(&cnt[uu], 1);
            if (s < UPAD) {
                ubkt[(size_t)uu * UPAD + s] = (unsigned short)ii;
            } else {
                int pp = atomicAdd(ovfc, 1);
                if (pp < OVF_CAP) ovf[pp] = make_int2(uu, N_USERS + ii);
            }
        } else {
            int loc = rec >> 17;
            int uu  = rec & 0x1FFFF;
            int ii  = p * ICH + loc;
            int s = atomicAdd(&cnt[N_USERS + ii], 1);
            if (s < IPAD) {
                ibkt[(size_t)ii * IPAD + s] = (unsigned int)uu;
            } else {
                int pp = atomicAdd(ovfc, 1);
                if (pp < OVF_CAP) ovf[pp] = make_int2(N_USERS + ii, uu);
            }
        }
    }
}

// ---------------------------------------------------------------------------
// Unified gather over all NR rows: wave per row, 8 neighbors/iter, chase-free.
// ---------------------------------------------------------------------------
template<int UP, int IP>
__global__ void gatherA_kernel(const unsigned short* __restrict__ xh,
                               const float4* __restrict__ scal,
                               const int* __restrict__ cnt,
                               const unsigned short* __restrict__ ubkt,
                               const unsigned int* __restrict__ ibkt,
                               float* __restrict__ out) {
    int gid  = blockIdx.x * blockDim.x + threadIdx.x;
    int r    = gid >> 6;
    int lane = gid & 63;
    if (r >= NR) return;

    int g = lane >> 3;
    int q = lane & 7;

    float4 sc = scal[r];
    uint4 hs = *(const uint4*)(xh + (size_t)r * D + q * 8);
    float xs0 = BF_LO(hs.x), xs1 = BF_HI(hs.x);
    float xs2 = BF_LO(hs.y), xs3 = BF_HI(hs.y);
    float xs4 = BF_LO(hs.z), xs5 = BF_HI(hs.z);
    float xs6 = BF_LO(hs.w), xs7 = BF_HI(hs.w);

    float a0=0.f,a1=0.f,a2=0.f,a3=0.f,a4=0.f,a5=0.f,a6=0.f,a7=0.f;

    if (r < N_USERS) {
        int deg = cnt[r];
        if (deg > UP) deg = UP;
        int iters = (deg + 7) >> 3;
        for (int it = 0; it < iters; ++it) {
            int idx = it * 8 + g;
            bool valid = (idx < deg);
            int nb = N_USERS + (int)ubkt[(size_t)r * UP + (valid ? idx : 0)];

            float4 so = scal[nb];
            uint4 ho = *(const uint4*)(xh + (size_t)nb * D + q * 8);
            float o0 = BF_LO(ho.x), o1 = BF_HI(ho.x);
            float o2 = BF_LO(ho.y), o3 = BF_HI(ho.y);
            float o4 = BF_LO(ho.z), o5 = BF_HI(ho.z);
            float o6 = BF_LO(ho.w), o7 = BF_HI(ho.w);

            float p = xs0*o0 + xs1*o1 + xs2*o2 + xs3*o3
                    + xs4*o4 + xs5*o5 + xs6*o6 + xs7*o7;
            p += __shfl_xor(p, 1);
            p += __shfl_xor(p, 2);
            p += __shfl_xor(p, 4);

            float sv  = p * sc.x * so.x - sc.z;
            float sig = 1.0f / (1.0f + __expf(-sv));
            float w   = 4.0f * sig * (1.0f - sig) * sc.y * so.y;
            w = valid ? w : 0.0f;

            a0 = fmaf(w, o0, a0); a1 = fmaf(w, o1, a1);
            a2 = fmaf(w, o2, a2); a3 = fmaf(w, o3, a3);
            a4 = fmaf(w, o4, a4); a5 = fmaf(w, o5, a5);
            a6 = fmaf(w, o6, a6); a7 = fmaf(w, o7, a7);
        }
    } else {
        int ri = r - N_USERS;
        int deg = cnt[r];
        if (deg > IP) deg = IP;
        int iters = (deg + 7) >> 3;
        for (int it = 0; it < iters; ++it) {
            int idx = it * 8 + g;
            bool valid = (idx < deg);
            int nb = (int)ibkt[(size_t)ri * IP + (valid ? idx : 0)];

            float4 so = scal[nb];
            uint4 ho = *(const uint4*)(xh + (size_t)nb * D + q * 8);
            float o0 = BF_LO(ho.x), o1 = BF_HI(ho.x);
            float o2 = BF_LO(ho.y), o3 = BF_HI(ho.y);
            float o4 = BF_LO(ho.z), o5 = BF_HI(ho.z);
            float o6 = BF_LO(ho.w), o7 = BF_HI(ho.w);

            float p = xs0*o0 + xs1*o1 + xs2*o2 + xs3*o3
                    + xs4*o4 + xs5*o5 + xs6*o6 + xs7*o7;
            p += __shfl_xor(p, 1);
            p += __shfl_xor(p, 2);
            p += __shfl_xor(p, 4);

            float sv  = p * sc.x * so.x - so.z;
            float sig = 1.0f / (1.0f + __expf(-sv));
            float w   = 4.0f * sig * (1.0f - sig) * sc.y * so.y;
            w = valid ? w : 0.0f;

            a0 = fmaf(w, o0, a0); a1 = fmaf(w, o1, a1);
            a2 = fmaf(w, o2, a2); a3 = fmaf(w, o3, a3);
            a4 = fmaf(w, o4, a4); a5 = fmaf(w, o5, a5);
            a6 = fmaf(w, o6, a6); a7 = fmaf(w, o7, a7);
        }
    }

    #pragma unroll
    for (int m = 8; m <= 32; m <<= 1) {
        a0 += __shfl_xor(a0, m); a1 += __shfl_xor(a1, m);
        a2 += __shfl_xor(a2, m); a3 += __shfl_xor(a3, m);
        a4 += __shfl_xor(a4, m); a5 += __shfl_xor(a5, m);
        a6 += __shfl_xor(a6, m); a7 += __shfl_xor(a7, m);
    }

    if (g == 0) {
        float4* o4p = (float4*)(out + (size_t)r * D + q * 8);
        o4p[0] = make_float4(a0, a1, a2, a3);
        o4p[1] = make_float4(a4, a5, a6, a7);
    }
}

// ---------------------------------------------------------------------------
// Overflow fixer: entries are (dst_row, nbr_row); beta = scal[d].z+scal[n].z
// (exactly one side is a user row). Recompute w in fp32, atomic-add one row.
// ---------------------------------------------------------------------------
__global__ void ovf2_kernel(const float* __restrict__ x,
                            const float4* __restrict__ scal,
                            const int* __restrict__ ovfc,
                            const int2* __restrict__ ovf,
                            float* __restrict__ out) {
    int n = *ovfc;
    if (n > OVF_CAP) n = OVF_CAP;
    int gid  = blockIdx.x * blockDim.x + threadIdx.x;
    int wave = gid >> 6;
    int lane = gid & 63;
    int nw   = (gridDim.x * blockDim.x) >> 6;

    for (int k = wave; k < n; k += nw) {
        int d  = ovf[k].x;
        int nb = ovf[k].y;
        float xd = x[(size_t)d * D + lane];
        float xn = x[(size_t)nb * D + lane];
        float p = xd * xn;
        #pragma unroll
        for (int m = 32; m >= 1; m >>= 1) p += __shfl_xor(p, m);
        float4 sd = scal[d];
        float4 sn = scal[nb];
        float sv  = p * sd.x * sn.x - (sd.z + sn.z);
        float sig = 1.0f / (1.0f + __expf(-sv));
        float w   = 4.0f * sig * (1.0f - sig) * sd.y * sn.y;
        atomicAdd(&out[(size_t)d * D + lane], w * xn);
    }
}

// ---------------------------------------------------------------------------
// Tier-A fallback: round-6 proven single-pass XCD-partitioned fill.
// ---------------------------------------------------------------------------
__global__ void fillx_kernel(const int* __restrict__ u,
                             const int* __restrict__ i,
                             int* __restrict__ cnt,
                             unsigned short* __restrict__ ubkt,
                             unsigned int* __restrict__ ibkt,
                             int* __restrict__ ovfc,
                             int2* __restrict__ ovf) {
    int p   = blockIdx.x & 7;
    int qb  = blockIdx.x >> 3;
    int tid = qb * blockDim.x + threadIdx.x;
    const int stride = 256 * 256;
    int ulo = p * UCH, uhi = ulo + UCH;
    int ilo = p * ICH, ihi = ilo + ICH;

    for (int e = tid; e < N_EDGES; e += stride) {
        int uu = __builtin_nontemporal_load(u + e);
        int ii = __builtin_nontemporal_load(i + e);
        if (uu >= ulo && uu < uhi) {
            int s = atomicAdd(&cnt[uu], 1);
            if (s < A_UPAD) ubkt[(size_t)uu * A_UPAD + s] = (unsigned short)ii;
            else { int pp = atomicAdd(ovfc, 1);
                   if (pp < OVF_CAP) ovf[pp] = make_int2(uu, N_USERS + ii); }
        }
        if (ii >= ilo && ii < ihi) {
            int s = atomicAdd(&cnt[N_USERS + ii], 1);
            if (s < A_IPAD) ibkt[(size_t)ii * A_IPAD + s] = (unsigned int)uu;
            else { int pp = atomicAdd(ovfc, 1);
                   if (pp < OVF_CAP) ovf[pp] = make_int2(N_USERS + ii, uu); }
        }
    }
}

// ---------------------------------------------------------------------------
// Minimal atomic fallback (tiny workspace)
// ---------------------------------------------------------------------------
__global__ void norm_kernel(const float* __restrict__ x,
                            float* __restrict__ invn, int nrows) {
    int gid  = blockIdx.x * blockDim.x + threadIdx.x;
    int wave = gid >> 6, lane = gid & 63;
    if (wave >= nrows) return;
    float v  = x[wave * D + lane];
    float ss = v * v;
    #pragma unroll
    for (int m = 32; m >= 1; m >>= 1) ss += __shfl_xor(ss, m);
    if (lane == 0) invn[wave] = 1.0f / fmaxf(sqrtf(ss), EPS);
}

__global__ void edge_kernel(const float* __restrict__ x,
                            const float* __restrict__ beta,
                            const float* __restrict__ du,
                            const float* __restrict__ di,
                            const int* __restrict__ u,
                            const int* __restrict__ i,
                            const float* __restrict__ invn,
                            float* __restrict__ out) {
    int gid  = blockIdx.x * blockDim.x + threadIdx.x;
    int wave = gid >> 6, lane = gid & 63;
    if (wave >= N_EDGES) return;
    int uu = u[wave], ii = i[wave];
    float xu = x[uu * D + lane];
    float xi = x[(N_USERS + ii) * D + lane];
    float p = xu * xi;
    #pragma unroll
    for (int m = 32; m >= 1; m >>= 1) p += __shfl_xor(p, m);
    float s   = p * invn[uu] * invn[N_USERS + ii] - beta[uu];
    float sig = 1.0f / (1.0f + __expf(-s));
    float w   = 4.0f * sig * (1.0f - sig) * rsqrtf(du[uu]) * rsqrtf(di[ii]);
    atomicAdd(&out[uu * D + lane],             w * xi);
    atomicAdd(&out[(N_USERS + ii) * D + lane], w * xu);
}

// ---------------------------------------------------------------------------
extern "C" void kernel_launch(void* const* d_in, const int* in_sizes, int n_in,
                              void* d_out, int out_size, void* d_ws, size_t ws_size,
                              hipStream_t stream) {
    const float* x    = (const float*)d_in[0];
    const float* beta = (const float*)d_in[1];
    const float* du   = (const float*)d_in[2];
    const float* di   = (const float*)d_in[3];
    const int*   u    = (const int*)d_in[4];
    const int*   i    = (const int*)d_in[5];
    float* out = (float*)d_out;
    char*  ws  = (char*)d_ws;

    if (ws_size >= (size_t)WS_P) {
        float4*         scal = (float4*)(ws + SCAL_OFF);
        unsigned short* xh   = (unsigned short*)(ws + XH_OFF);
        int*            cnt  = (int*)(ws + CNT_OFF);
        unsigned short* ubkt = (unsigned short*)(ws + UBKT_OFF);
        unsigned int*   ibkt = (unsigned int*)(ws + IBKT_OFF);
        unsigned int*   part = (unsigned int*)(ws + PART_OFF);
        int*            ucur = (int*)(ws + UCUR_OFF);
        int*            icur = (int*)(ws + ICUR_OFF);
        int*            ovfc = (int*)(ws + OVFC_OFF);
        int2*           ovf  = (int2*)(ws + OVF_OFF);

        hipMemsetAsync(cnt, 0, (size_t)NR * sizeof(int), stream);
        init_kernel<<<1, 64, 0, stream>>>(ucur, icur, ovfc);
        prep_kernel<<<(NR + 3) / 4, 256, 0, stream>>>(x, beta, du, di, scal, xh);

        part_kernel<0><<<PART_BLOCKS, 256, 0, stream>>>(u, i, ucur, part, ovfc, ovf);
        fillp_kernel<0><<<FILLP_BLOCKS, 256, 0, stream>>>(part, ucur, cnt, ubkt, ibkt, ovfc, ovf);
        part_kernel<1><<<PART_BLOCKS, 256, 0, stream>>>(u, i, icur, part, ovfc, ovf);
        fillp_kernel<1><<<FILLP_BLOCKS, 256, 0, stream>>>(part, icur, cnt, ubkt, ibkt, ovfc, ovf);

        gatherA_kernel<UPAD, IPAD><<<(NR + 3) / 4, 256, 0, stream>>>(
            xh, scal, cnt, ubkt, ibkt, out);
        ovf2_kernel<<<64, 256, 0, stream>>>(x, scal, ovfc, ovf, out);
    } else if (ws_size >= (size_t)WS_A) {
        float4*         scal = (float4*)(ws + A_SCAL);
        unsigned short* xh   = (unsigned short*)(ws + A_XH);
        int*            cnt  = (int*)(ws + A_CNT);
        unsigned short* ubkt = (unsigned short*)(ws + A_UBKT);
        unsigned int*   ibkt = (unsigned int*)(ws + A_IBKT);
        int*            ovfc = (int*)(ws + A_OVFC);
        int2*           ovf  = (int2*)(ws + A_OVF);

        hipMemsetAsync(cnt, 0, (size_t)NR * sizeof(int), stream);
        hipMemsetAsync(ovfc, 0, sizeof(int), stream);
        prep_kernel<<<(NR + 3) / 4, 256, 0, stream>>>(x, beta, du, di, scal, xh);
        fillx_kernel<<<2048, 256, 0, stream>>>(u, i, cnt, ubkt, ibkt, ovfc, ovf);
        gatherA_kernel<A_UPAD, A_IPAD><<<(NR + 3) / 4, 256, 0, stream>>>(
            xh, scal, cnt, ubkt, ibkt, out);
        ovf2_kernel<<<64, 256, 0, stream>>>(x, scal, ovfc, ovf, out);
    } else {
        float* invn = (float*)ws;
        hipMemsetAsync(d_out, 0, (size_t)out_size * sizeof(float), stream);
        norm_kernel<<<(NR + 3) / 4, 256, 0, stream>>>(x, invn, NR);
        edge_kernel<<<(N_EDGES + 3) / 4, 256, 0, stream>>>(x, beta, du, di, u, i, invn, out);
    }
}